// Round 5
// baseline (1144.454 us; speedup 1.0000x reference)
//
#include <hip/hip_runtime.h>
#include <math.h>

#define FRAME 128
#define HOPW 64
#define SLEN 65536
#define IRLEN 1024
#define NFB 1006          // feedback iterations
#define RMASK 2047
#define PI_D 3.14159265358979323846

__device__ __forceinline__ float clip1(float v) { return fminf(1.0f, fmaxf(-1.0f, v)); }

// Raw barrier: drains LDS ops only; global loads/stores stay in flight.
__device__ __forceinline__ void loop_barrier() {
    __builtin_amdgcn_sched_barrier(0);
    asm volatile("s_waitcnt lgkmcnt(0)" ::: "memory");
    __builtin_amdgcn_s_barrier();
    __builtin_amdgcn_sched_barrier(0);
}

// Single-barrier-per-iteration howling loop.
// 768 threads = 12 waves. kg = tid/192 (wave-uniform 32-tap group), ob = tid%192
// -> 6 conv outputs/thread. w_i lives in ONE register per thread (wreg): lane l
// of a kg-wave holds w_i[32*kg + (l&31)]; FMA taps come via readlane.
// Ring invariant: slot at x-pos X holds raw + all conv_j with (X-base_j-64) in
// [128,1152) (bulk-applied); the two newest convs' heads are added in-register.
__global__ __launch_bounds__(768) void howl_fused(const float* __restrict__ x,
                                                  const float* __restrict__ ir,
                                                  float* __restrict__ out) {
    __shared__ float ring[2048];
    __shared__ float part[3][4][1152];   // triple-buffered conv partials
    __shared__ float irl[IRLEN];
    __shared__ float tailb[2][HOPW];     // w_i[64:128] handoff, double-buffered
    __shared__ float red1[1024];
    __shared__ float red2[1024];
    __shared__ float invfs;

    const int tid = threadIdx.x;
    const int lane = tid & 63;
    const int wvid = tid >> 6;
    const int kg = tid / 192;
    const int ob = tid % 192;
    const int q = ob * 6;
    const int lo = q - kg * 32 - 31;
    const int s = kg * 32 + (lane & 31);   // this wave's w-slice index

    // ---- prologue: stage IR + raw x window ----
    for (int idx = tid; idx < IRLEN; idx += 768) irl[idx] = ir[idx];
    for (int idx = tid; idx < 1216; idx += 768) ring[idx] = x[idx];  // raw
    if (tid >= 513) { red1[tid] = -INFINITY; red2[tid] = 0.f; }
    if (tid < 256) { red1[768 + tid] = -INFINITY; red2[768 + tid] = 0.f; }
    __syncthreads();

    // ---- DFT power spectrum (4-way ILP recurrence, double precision) ----
    if (tid < 513) {
        double th = -2.0 * PI_D * (double)tid / 1024.0;
        double c4 = cos(4.0 * th), s4 = sin(4.0 * th);
        double wr0 = 1.0,           wi0 = 0.0;
        double wr1 = cos(th),       wi1 = sin(th);
        double wr2 = cos(2.0 * th), wi2 = sin(2.0 * th);
        double wr3 = cos(3.0 * th), wi3 = sin(3.0 * th);
        double ar0 = 0, ai0 = 0, ar1 = 0, ai1 = 0, ar2 = 0, ai2 = 0, ar3 = 0, ai3 = 0;
        for (int m = 0; m < 256; ++m) {
            double x0 = irl[4 * m], x1 = irl[4 * m + 1], x2 = irl[4 * m + 2], x3 = irl[4 * m + 3];
            ar0 += x0 * wr0; ai0 += x0 * wi0;
            ar1 += x1 * wr1; ai1 += x1 * wi1;
            ar2 += x2 * wr2; ai2 += x2 * wi2;
            ar3 += x3 * wr3; ai3 += x3 * wi3;
            double t;
            t = wr0 * c4 - wi0 * s4; wi0 = wr0 * s4 + wi0 * c4; wr0 = t;
            t = wr1 * c4 - wi1 * s4; wi1 = wr1 * s4 + wi1 * c4; wr1 = t;
            t = wr2 * c4 - wi2 * s4; wi2 = wr2 * s4 + wi2 * c4; wr2 = t;
            t = wr3 * c4 - wi3 * s4; wi3 = wr3 * s4 + wi3 * c4; wr3 = t;
        }
        double re = (ar0 + ar1) + (ar2 + ar3);
        double im = (ai0 + ai1) + (ai2 + ai3);
        float mag = (float)sqrt(re * re + im * im);
        float pw = mag * mag;
        double ph = atan2(im, re);
        int ok = (ph > -0.1 && ph < 0.1) ? 1 : 0;
        red1[tid] = ok ? pw : -INFINITY;
        red2[tid] = pw;
    }
    __syncthreads();
    for (int st = 512; st > 0; st >>= 1) {
        if (tid < st) {
            red1[tid] = fmaxf(red1[tid], red1[tid + st]);
            red2[tid] = red2[tid] + red2[tid + st];
        }
        __syncthreads();
    }
    if (tid == 0) {
        float peak = red1[0];
        float MLG = red2[0] / 513.0f;
        float MSG = -10.0f * log10f(peak / MLG);
        float target_gain = MSG + 2.0f;
        float mean_gain = 10.0f * log10f(MLG);
        invfs = powf(0.5f, (target_gain - mean_gain) / 6.0f);
    }
    __syncthreads();

    const float fbc = invfs;
    float wir[37];
#pragma unroll
    for (int j = 0; j < 37; ++j) {
        int idx = lo + j;
        wir[j] = (idx >= 0 && idx < IRLEN) ? irl[idx] / fbc : 0.f;
    }

    const float hwv = (float)(0.5 * (1.0 - cos(PI_D * (double)s / 64.0)));

    // initial frame w_0 from RAW x (per reference)
    float wreg = hwv * ring[s];
    if ((wvid == 0 || wvid == 3) && lane < 32) out[s] = clip1(wreg);       // block 0
    if ((wvid == 6 || wvid == 9) && lane < 32) tailb[0][s - 64] = wreg;    // w_0 tail
    float xv = 0.f;
    if (wvid == 4) xv = x[1216 + lane];    // prefetch for body-0 commit
    __syncthreads();

    auto body = [&](int i, float (*cur)[1152], const float (*prev)[1152], int first) {
        const int base = i * HOPW;

        // x-commit + prefetch (wave 4)
        if (wvid == 4) {
            int pos = base + 1216 + lane;
            if (pos < SLEN) ring[pos & RMASK] = clip1(xv);
            int np = pos + HOPW;
            xv = (np < SLEN) ? x[np] : 0.f;
        }

        // bulk ring apply of conv_{i-1}, p in [128,1152)  (waves 2,5,8,11)
        if (!first && (wvid == 2 || wvid == 5 || wvid == 8 || wvid == 11)) {
            int c = ((wvid - 2) / 3) * 64 + lane;
            int p = 128 + 4 * c;
            float4 g0 = *(const float4*)&prev[0][p];
            float4 g1 = *(const float4*)&prev[1][p];
            float4 g2 = *(const float4*)&prev[2][p];
            float4 g3 = *(const float4*)&prev[3][p];
            int slot = (base + p) & RMASK;
            float4 r = *(float4*)&ring[slot];
            r.x = clip1(r.x + (((g0.x + g1.x) + g2.x) + g3.x));
            r.y = clip1(r.y + (((g0.y + g1.y) + g2.y) + g3.y));
            r.z = clip1(r.z + (((g0.z + g1.z) + g2.z) + g3.z));
            r.w = clip1(r.w + (((g0.w + g1.w) + g2.w) + g3.w));
            *(float4*)&ring[slot] = r;
        }

        // conv partials for frame i (taps via readlane from wreg)
        float a0 = 0, a1 = 0, a2 = 0, a3 = 0, a4 = 0, a5 = 0;
#pragma unroll
        for (int kk = 0; kk < 32; ++kk) {
            float sc = __int_as_float(__builtin_amdgcn_readlane(__float_as_int(wreg), 31 - kk));
            a0 = fmaf(sc, wir[kk + 0], a0);
            a1 = fmaf(sc, wir[kk + 1], a1);
            a2 = fmaf(sc, wir[kk + 2], a2);
            a3 = fmaf(sc, wir[kk + 3], a3);
            a4 = fmaf(sc, wir[kk + 4], a4);
            a5 = fmaf(sc, wir[kk + 5], a5);
        }
        float* pw = &cur[kg][q];
        *(float2*)(pw + 0) = make_float2(a0, a1);
        *(float2*)(pw + 2) = make_float2(a2, a3);
        *(float2*)(pw + 4) = make_float2(a4, a5);

        loop_barrier();

        // (A): each wave computes its own w_{i+1} slice into wreg
        float rr = ring[(base + 64 + s) & RMASK];
        float c0 = cur[0][s], c1 = cur[1][s], c2 = cur[2][s], c3 = cur[3][s];
        float sc4 = ((c0 + c1) + c2) + c3;
        if (kg < 2) {   // s in [0,64): head needs conv_{i-1}[64+s] AND conv_i[s]
            float v;
            if (first) {
                v = clip1(rr + sc4);
            } else {
                float m0 = prev[0][64 + s], m1 = prev[1][64 + s];
                float m2 = prev[2][64 + s], m3 = prev[3][64 + s];
                float sm = ((m0 + m1) + m2) + m3;
                v = clip1(clip1(rr + sm) + sc4);
            }
            float wn = hwv * v;
            if ((wvid == 0 || wvid == 3) && lane < 32) {
                float told = tailb[i & 1][s];
                out[base + 64 + s] = clip1(wn + told);   // OLA block i+1
            }
            wreg = wn;
        } else {        // s in [64,128): ring already has conv_{i-1} (bulk, this body)
            float v = clip1(rr + sc4);
            float wn = hwv * v;
            if ((wvid == 6 || wvid == 9) && lane < 32) tailb[(i + 1) & 1][s - 64] = wn;
            wreg = wn;
        }
    };

    float (*P0)[1152] = part[0];
    float (*P1)[1152] = part[1];
    float (*P2)[1152] = part[2];

    body(0, P0, P2, 1);
#pragma unroll 1
    for (int i = 1; i < NFB; i += 3) {   // 1005 = 3*335 iterations
        body(i,     P1, P0, 0);
        body(i + 1, P2, P1, 0);
        body(i + 2, P0, P2, 0);
    }

    // ---- epilogue: block 1007 (last frame tail) + zero tail ----
    if ((wvid == 6 || wvid == 9) && lane < 32) out[64448 + (s - 64)] = clip1(wreg);
    for (int idx = 64512 + tid; idx < SLEN; idx += 768) out[idx] = 0.f;
}

extern "C" void kernel_launch(void* const* d_in, const int* in_sizes, int n_in,
                              void* d_out, int out_size, void* d_ws, size_t ws_size,
                              hipStream_t stream) {
    const float* x = (const float*)d_in[0];
    const float* ir = (const float*)d_in[1];
    float* out = (float*)d_out;
    (void)d_ws; (void)ws_size; (void)in_sizes; (void)n_in; (void)out_size;

    hipLaunchKernelGGL(howl_fused, dim3(1), dim3(768), 0, stream, x, ir, out);
}